// Round 1
// baseline (240.981 us; speedup 1.0000x reference)
//
#include <hip/hip_runtime.h>

#define T_STEPS 512
#define BATCH   8192

// Broadcast lane (beta, K)'s value to all 8 lanes of its group (pull-swizzle).
template<int K>
__device__ __forceinline__ float bcast8(float v) {
    return __int_as_float(__builtin_amdgcn_ds_swizzle(__float_as_int(v), (K << 5) | 0x18));
}
__device__ __forceinline__ float bperm(int byteIdx, float v) {
    return __int_as_float(__builtin_amdgcn_ds_bpermute(byteIdx, __float_as_int(v)));
}
__device__ __forceinline__ float rcp_hw(float v)  { return __builtin_amdgcn_rcpf(v); }
__device__ __forceinline__ float exp2_hw(float v) { return __builtin_amdgcn_exp2f(v); }

__global__ __launch_bounds__(256) void lstm_g8_kernel(
    const float* __restrict__ x,   const float* __restrict__ Wih,
    const float* __restrict__ Whh, const float* __restrict__ bih,
    const float* __restrict__ bhh, const float* __restrict__ W1,
    const float* __restrict__ b1v, const float* __restrict__ W2,
    const float* __restrict__ b2v, float* __restrict__ out)
{
    const int tid  = blockIdx.x * 256 + threadIdx.x;
    const int lane = threadIdx.x & 63;
    const int sig  = lane & 7;        // gate slot 0..7
    const int beta = lane >> 3;       // batch-in-wave (uses lane bits [5:3])
    const int wid  = tid >> 6;
    const int b    = wid * 8 + (beta & 7);

    // --- per-lane weights: rows sig, sig+8, sig+16 of combined [W_ih | W_hh] ---
    float w[3][12], bias[3], em[3], am[3], cm[3];
    #pragma unroll
    for (int j = 0; j < 3; ++j) {
        const int r = sig + 8 * j;
        #pragma unroll
        for (int k = 0; k < 6; ++k) {
            w[j][k]     = Wih[r * 6 + k];
            w[j][6 + k] = Whh[r * 6 + k];
        }
        bias[j] = bih[r] + bhh[r];
        // rows 12..17 are the g-gate (tanh); others sigmoid.
        const bool g_row = (r >= 12) && (r < 18);
        em[j] = g_row ? -2.8853900817779268f : -1.4426950408889634f; // -m*log2(e)
        am[j] = g_row ?  2.0f : 1.0f;
        cm[j] = g_row ? -1.0f : 0.0f;
    }

    // --- precomputed gather indices (byte addresses for ds_bpermute) ---
    // dest lane d needs: f = row 6+d  (src sig: d<2 ? 6+d : d-2)
    //                    g = row 12+d (src sig: d<4 ? 4+d : d-4)
    //                    o = row 18+d (src sig: 2+d)
    const int base  = lane & ~7;
    const int idx_f = (base + (sig < 2 ? 6 + sig : sig - 2)) << 2;
    const int idx_g = (base + (sig < 4 ? 4 + sig : sig - 4)) << 2;
    const int idx_o = (base + ((sig + 2) & 7)) << 2;
    const bool lo4  = (sig < 4);

    // per-lane x stream: x[b][t][min(sig,5)], stride 6 floats per t
    const float* xp = x + b * (T_STEPS * 6) + (sig < 6 ? sig : 5);

    // 4-deep prefetch pipeline to cover HBM latency
    float pf0 = xp[0 * 6], pf1 = xp[1 * 6], pf2 = xp[2 * 6], pf3 = xp[3 * 6];

    float c = 0.0f, h = 0.0f;

    auto step = [&](float& pfreg, int t) {
        const float xv = pfreg;
        const int tn = t + 4;
        const int tc = (tn < T_STEPS) ? tn : (T_STEPS - 1);
        pfreg = xp[tc * 6];

        float in[12];
        in[0] = bcast8<0>(xv); in[1] = bcast8<1>(xv); in[2] = bcast8<2>(xv);
        in[3] = bcast8<3>(xv); in[4] = bcast8<4>(xv); in[5] = bcast8<5>(xv);
        in[6]  = bcast8<0>(h); in[7]  = bcast8<1>(h); in[8]  = bcast8<2>(h);
        in[9]  = bcast8<3>(h); in[10] = bcast8<4>(h); in[11] = bcast8<5>(h);

        float act[3];
        #pragma unroll
        for (int j = 0; j < 3; ++j) {
            float a = bias[j];
            #pragma unroll
            for (int k = 0; k < 12; ++k) a = fmaf(w[j][k], in[k], a);
            // sigmoid / tanh via a*rcp(1+exp2(em*x)) + c
            act[j] = fmaf(am[j], rcp_hw(1.0f + exp2_hw(a * em[j])), cm[j]);
        }

        const float fv = bperm(idx_f, lo4 ? act[1] : act[0]);
        const float gv = bperm(idx_g, lo4 ? act[2] : act[1]);
        const float ov = bperm(idx_o, act[2]);

        c = fmaf(fv, c, act[0] * gv);
        const float th = fmaf(2.0f, rcp_hw(1.0f + exp2_hw(c * -2.8853900817779268f)), -1.0f);
        h = ov * th;
    };

    for (int t4 = 0; t4 < T_STEPS; t4 += 4) {
        step(pf0, t4 + 0);
        step(pf1, t4 + 1);
        step(pf2, t4 + 2);
        step(pf3, t4 + 3);
    }

    // --- head: h(6) -> 4 -> 2 -> softmax (redundant per group, store from sig==0) ---
    float hf[6];
    hf[0] = bcast8<0>(h); hf[1] = bcast8<1>(h); hf[2] = bcast8<2>(h);
    hf[3] = bcast8<3>(h); hf[4] = bcast8<4>(h); hf[5] = bcast8<5>(h);

    float o1[4];
    #pragma unroll
    for (int j = 0; j < 4; ++j) {
        float a = b1v[j];
        #pragma unroll
        for (int k = 0; k < 6; ++k) a = fmaf(W1[j * 6 + k], hf[k], a);
        o1[j] = a;
    }
    float o2[2];
    #pragma unroll
    for (int m = 0; m < 2; ++m) {
        float a = b2v[m];
        #pragma unroll
        for (int j = 0; j < 4; ++j) a = fmaf(W2[m * 4 + j], o1[j], a);
        o2[m] = a;
    }
    const float mx = fmaxf(o2[0], o2[1]);
    const float e0 = exp2_hw((o2[0] - mx) * 1.4426950408889634f);
    const float e1 = exp2_hw((o2[1] - mx) * 1.4426950408889634f);
    const float s  = rcp_hw(e0 + e1);

    if (sig == 0) {
        ((float2*)out)[b] = make_float2(e0 * s, e1 * s);
    }
}

extern "C" void kernel_launch(void* const* d_in, const int* in_sizes, int n_in,
                              void* d_out, int out_size, void* d_ws, size_t ws_size,
                              hipStream_t stream) {
    const float* x   = (const float*)d_in[0];
    const float* Wih = (const float*)d_in[1];
    const float* Whh = (const float*)d_in[2];
    const float* bih = (const float*)d_in[3];
    const float* bhh = (const float*)d_in[4];
    const float* W1  = (const float*)d_in[5];
    const float* b1v = (const float*)d_in[6];
    const float* W2  = (const float*)d_in[7];
    const float* b2v = (const float*)d_in[8];
    float* out = (float*)d_out;

    // 8 batch per wave, 4 waves per block -> 32 batch per block -> 256 blocks
    const int blocks = BATCH / 32;
    lstm_g8_kernel<<<blocks, 256, 0, stream>>>(x, Wih, Whh, bih, bhh, W1, b1v, W2, b2v, out);
}

// Round 2
// 133.744 us; speedup vs baseline: 1.8018x; 1.8018x over previous
//
#include <hip/hip_runtime.h>

#define T_STEPS 512
#define BATCH   8192

// Broadcast lane (group_base + K)'s value to all 8 lanes of its group.
template<int K>
__device__ __forceinline__ float bcast8(float v) {
    return __int_as_float(__builtin_amdgcn_ds_swizzle(__float_as_int(v), (K << 5) | 0x18));
}
__device__ __forceinline__ float rcp_hw(float v)  { return __builtin_amdgcn_rcpf(v); }
__device__ __forceinline__ float exp2_hw(float v) { return __builtin_amdgcn_exp2f(v); }

__device__ __forceinline__ float sigm_hw(float a) {
    // 1 / (1 + exp(-a)) = rcp(1 + exp2(-a*log2(e)))
    return rcp_hw(1.0f + exp2_hw(a * -1.4426950408889634f));
}
__device__ __forceinline__ float tanh_fast(float a) {
    // 2/(1+exp2(-2a*log2e)) - 1
    return fmaf(2.0f, rcp_hw(1.0f + exp2_hw(a * -2.8853900817779268f)), -1.0f);
}

__global__ __launch_bounds__(256) void lstm_dsplit_kernel(
    const float* __restrict__ x,   const float* __restrict__ Wih,
    const float* __restrict__ Whh, const float* __restrict__ bih,
    const float* __restrict__ bhh, const float* __restrict__ W1,
    const float* __restrict__ b1v, const float* __restrict__ W2,
    const float* __restrict__ b2v, float* __restrict__ out)
{
    const int tid  = blockIdx.x * 256 + threadIdx.x;
    const int lane = threadIdx.x & 63;
    const int sig  = lane & 7;             // slot in 8-lane group
    const int d    = (sig < 6) ? sig : 5;  // hidden unit owned (lanes 6,7 duplicate d=5)
    const int wid  = tid >> 6;
    const int b    = wid * 8 + ((lane >> 3) & 7);

    // Lane d owns hidden unit d: gate rows i=d, f=6+d, g=12+d, o=18+d.
    // w[j][0..5] = W_ih row, w[j][6..11] = W_hh row.  j: 0=i,1=f,2=g,3=o
    float w[4][12], bias[4];
    #pragma unroll
    for (int j = 0; j < 4; ++j) {
        const int r = 6 * j + d;
        #pragma unroll
        for (int k = 0; k < 6; ++k) {
            w[j][k]     = Wih[r * 6 + k];
            w[j][6 + k] = Whh[r * 6 + k];
        }
        bias[j] = bih[r] + bhh[r];
    }

    // per-lane x stream: lane d reads x[b][t][d]
    const float* xp = x + b * (T_STEPS * 6) + d;

    // 8-deep prefetch pipeline (~7 steps of latency cover)
    float pf[8];
    #pragma unroll
    for (int i = 0; i < 8; ++i) pf[i] = xp[i * 6];

    // x(t=0) broadcast
    float inx[6];
    inx[0] = bcast8<0>(pf[0]); inx[1] = bcast8<1>(pf[0]); inx[2] = bcast8<2>(pf[0]);
    inx[3] = bcast8<3>(pf[0]); inx[4] = bcast8<4>(pf[0]); inx[5] = bcast8<5>(pf[0]);

    float c = 0.0f, h = 0.0f;

    auto step = [&](float& pfcur, float pfnext, int t) {
        // h broadcast (the only on-chain LDS op) — issue first
        float hh[6];
        hh[0] = bcast8<0>(h); hh[1] = bcast8<1>(h); hh[2] = bcast8<2>(h);
        hh[3] = bcast8<3>(h); hh[4] = bcast8<4>(h); hh[5] = bcast8<5>(h);

        // x-part accumulation for this step (no h dependency — schedulable early)
        float acc[4];
        #pragma unroll
        for (int j = 0; j < 4; ++j) {
            float a = bias[j];
            #pragma unroll
            for (int k = 0; k < 6; ++k) a = fmaf(w[j][k], inx[k], a);
            acc[j] = a;
        }

        // refill inx with x(t+1) from pfnext (off-chain)
        inx[0] = bcast8<0>(pfnext); inx[1] = bcast8<1>(pfnext); inx[2] = bcast8<2>(pfnext);
        inx[3] = bcast8<3>(pfnext); inx[4] = bcast8<4>(pfnext); inx[5] = bcast8<5>(pfnext);

        // prefetch x(t+8)
        const int tn = t + 8;
        const int tc = (tn < T_STEPS) ? tn : (T_STEPS - 1);
        pfcur = xp[tc * 6];

        // h-part accumulation (on-chain: 6-deep FMA per gate, 4-way ILP)
        #pragma unroll
        for (int j = 0; j < 4; ++j) {
            float a = acc[j];
            #pragma unroll
            for (int k = 0; k < 6; ++k) a = fmaf(w[j][6 + k], hh[k], a);
            acc[j] = a;
        }

        // activations & state (all local to the lane)
        const float iv = sigm_hw(acc[0]);
        const float fv = sigm_hw(acc[1]);
        const float gv = tanh_fast(acc[2]);
        const float ov = sigm_hw(acc[3]);
        c = fmaf(fv, c, iv * gv);
        h = ov * tanh_fast(c);
    };

    for (int t8 = 0; t8 < T_STEPS; t8 += 8) {
        step(pf[0], pf[1], t8 + 0);
        step(pf[1], pf[2], t8 + 1);
        step(pf[2], pf[3], t8 + 2);
        step(pf[3], pf[4], t8 + 3);
        step(pf[4], pf[5], t8 + 4);
        step(pf[5], pf[6], t8 + 5);
        step(pf[6], pf[7], t8 + 6);
        step(pf[7], pf[0], t8 + 7);
    }

    // --- head: h(6) -> 4 -> 2 -> softmax (redundant per group, store from sig==0) ---
    float hf[6];
    hf[0] = bcast8<0>(h); hf[1] = bcast8<1>(h); hf[2] = bcast8<2>(h);
    hf[3] = bcast8<3>(h); hf[4] = bcast8<4>(h); hf[5] = bcast8<5>(h);

    float o1[4];
    #pragma unroll
    for (int j = 0; j < 4; ++j) {
        float a = b1v[j];
        #pragma unroll
        for (int k = 0; k < 6; ++k) a = fmaf(W1[j * 6 + k], hf[k], a);
        o1[j] = a;
    }
    float o2[2];
    #pragma unroll
    for (int m = 0; m < 2; ++m) {
        float a = b2v[m];
        #pragma unroll
        for (int j = 0; j < 4; ++j) a = fmaf(W2[m * 4 + j], o1[j], a);
        o2[m] = a;
    }
    const float mx = fmaxf(o2[0], o2[1]);
    const float e0 = exp2_hw((o2[0] - mx) * 1.4426950408889634f);
    const float e1 = exp2_hw((o2[1] - mx) * 1.4426950408889634f);
    const float s  = rcp_hw(e0 + e1);

    if (sig == 0) {
        ((float2*)out)[b] = make_float2(e0 * s, e1 * s);
    }
}

extern "C" void kernel_launch(void* const* d_in, const int* in_sizes, int n_in,
                              void* d_out, int out_size, void* d_ws, size_t ws_size,
                              hipStream_t stream) {
    const float* x   = (const float*)d_in[0];
    const float* Wih = (const float*)d_in[1];
    const float* Whh = (const float*)d_in[2];
    const float* bih = (const float*)d_in[3];
    const float* bhh = (const float*)d_in[4];
    const float* W1  = (const float*)d_in[5];
    const float* b1v = (const float*)d_in[6];
    const float* W2  = (const float*)d_in[7];
    const float* b2v = (const float*)d_in[8];
    float* out = (float*)d_out;

    // 8 batch per wave, 4 waves per block -> 32 batch per block -> 256 blocks
    const int blocks = BATCH / 32;
    lstm_dsplit_kernel<<<blocks, 256, 0, stream>>>(x, Wih, Whh, bih, bhh, W1, b1v, W2, b2v, out);
}